// Round 1
// baseline (2357.293 us; speedup 1.0000x reference)
//
#include <hip/hip_runtime.h>
#include <math.h>

#define E_CNT 800000
#define G_CNT 1000000
#define EDGE_DIM 128
#define HIDDEN 256
#define HEADS 8
#define NUM_NODES 100000

#define ROWS 32      // groups per block
#define TPB 256      // 4 waves

__global__ void zero_deg_kernel(float* __restrict__ deg) {
    int i = blockIdx.x * blockDim.x + threadIdx.x;
    if (i < NUM_NODES) deg[i] = 0.0f;
}

__global__ void degree_kernel(const int* __restrict__ ei, float* __restrict__ deg) {
    int e = blockIdx.x * blockDim.x + threadIdx.x;
    if (e < E_CNT) {
        atomicAdd(&deg[ei[e]], 1.0f);          // edge_index[0][e]
        atomicAdd(&deg[ei[E_CNT + e]], 1.0f);  // edge_index[1][e]
    }
}

__launch_bounds__(TPB, 2)
__global__ void egis_main_kernel(
    const float* __restrict__ emb,   // (E, 128)
    const int*   __restrict__ eg,    // (G, 2)
    const int*   __restrict__ ei,    // (2, E)
    const float* __restrict__ W1, const float* __restrict__ b1,   // (256,256),(256)
    const float* __restrict__ W2, const float* __restrict__ b2,   // (256,8),(8)
    const float* __restrict__ Ws1, const float* __restrict__ bs1, // (4,64),(64)
    const float* __restrict__ Ws2, const float* __restrict__ bs2, // (64,1),(1)
    const float* __restrict__ Wc1, const float* __restrict__ bc1, // (9,128),(128)
    const float* __restrict__ Wc2, const float* __restrict__ bc2, // (128,1),(1)
    const float* __restrict__ deg,  // (NUM_NODES)
    float* __restrict__ out)        // (G)
{
    // pair rows (later reused to hold hidden activations). +4 pad keeps
    // float4 alignment while breaking the 1KB power-of-2 row stride.
    __shared__ __align__(16) float pairS[ROWS][HIDDEN + 4];
    __shared__ float compS[ROWS][HEADS];
    __shared__ float ssS[ROWS];
    __shared__ int g0S[ROWS], g1S[ROWS];

    const int tid = threadIdx.x;
    const int gbase = blockIdx.x * ROWS;

    if (tid < ROWS) {
        g0S[tid] = eg[(gbase + tid) * 2 + 0];
        g1S[tid] = eg[(gbase + tid) * 2 + 1];
    }
    __syncthreads();

    // ---- gather pair rows: row r = [emb[g0S[r]], emb[g1S[r]]], 256 floats ----
    {
        const float4* emb4 = (const float4*)emb;
        #pragma unroll
        for (int it = 0; it < (ROWS * 64) / TPB; ++it) {
            int idx = it * TPB + tid;
            int r = idx >> 6;          // row
            int c4 = idx & 63;         // float4 column within row
            float4 v;
            if (c4 < 32) v = emb4[(long)g0S[r] * 32 + c4];
            else         v = emb4[(long)g1S[r] * 32 + (c4 - 32)];
            *(float4*)&pairS[r][c4 * 4] = v;
        }
    }
    __syncthreads();

    // ---- hidden = relu(pair @ W1 + b1) ----
    // wave w owns rows w*8..w*8+7; lane owns output cols 4*lane..4*lane+3
    const int wave = tid >> 6;
    const int lane = tid & 63;

    float acc[8][4];
    {
        const float4 bv = ((const float4*)b1)[lane];
        #pragma unroll
        for (int r = 0; r < 8; ++r) {
            acc[r][0] = bv.x; acc[r][1] = bv.y; acc[r][2] = bv.z; acc[r][3] = bv.w;
        }
    }

    const float4* W14 = (const float4*)W1;   // W1[k][j] = W14[k*64 + j/4]
    for (int k0 = 0; k0 < HIDDEN; k0 += 4) {
        float4 w0 = W14[(k0 + 0) * 64 + lane];
        float4 w1 = W14[(k0 + 1) * 64 + lane];
        float4 w2 = W14[(k0 + 2) * 64 + lane];
        float4 w3 = W14[(k0 + 3) * 64 + lane];
        #pragma unroll
        for (int r = 0; r < 8; ++r) {
            float4 p = *(const float4*)&pairS[wave * 8 + r][k0];  // wave-uniform: LDS broadcast
            acc[r][0] += p.x * w0.x + p.y * w1.x + p.z * w2.x + p.w * w3.x;
            acc[r][1] += p.x * w0.y + p.y * w1.y + p.z * w2.y + p.w * w3.y;
            acc[r][2] += p.x * w0.z + p.y * w1.z + p.z * w2.z + p.w * w3.z;
            acc[r][3] += p.x * w0.w + p.y * w1.w + p.z * w2.w + p.w * w3.w;
        }
    }

    __syncthreads();   // all waves finished reading pairS
    #pragma unroll
    for (int r = 0; r < 8; ++r) {
        float4 hv;
        hv.x = fmaxf(acc[r][0], 0.0f);
        hv.y = fmaxf(acc[r][1], 0.0f);
        hv.z = fmaxf(acc[r][2], 0.0f);
        hv.w = fmaxf(acc[r][3], 0.0f);
        *(float4*)&pairS[wave * 8 + r][4 * lane] = hv;   // h overwrites pair
    }
    __syncthreads();

    // ---- comp = relu(h @ W2 + b2), 8 heads per row ----
    {
        int r = tid >> 3;       // 0..31
        int hh = tid & 7;       // head
        float c = b2[hh];
        #pragma unroll 8
        for (int j = 0; j < HIDDEN; ++j)
            c += pairS[r][j] * W2[j * HEADS + hh];
        compS[r][hh] = fmaxf(c, 0.0f);
    }

    // ---- structural score: ss = relu(sf @ Ws1 + bs1) @ Ws2 + bs2 ----
    {
        int r = tid >> 3;       // 0..31
        int u8 = tid & 7;       // 8 threads split the 64 hidden units
        int g0 = g0S[r], g1 = g1S[r];
        float s0 = deg[ei[g0]];
        float s1 = deg[ei[E_CNT + g0]];
        float s2 = deg[ei[g1]];
        float s3 = deg[ei[E_CNT + g1]];
        float part = 0.0f;
        #pragma unroll
        for (int i = 0; i < 8; ++i) {
            int u = u8 * 8 + i;
            float h = bs1[u] + s0 * Ws1[0 * 64 + u] + s1 * Ws1[1 * 64 + u]
                             + s2 * Ws1[2 * 64 + u] + s3 * Ws1[3 * 64 + u];
            part += fmaxf(h, 0.0f) * Ws2[u];
        }
        part += __shfl_xor(part, 1);
        part += __shfl_xor(part, 2);
        part += __shfl_xor(part, 4);
        if (u8 == 0) ssS[r] = part + bs2[0];
    }
    __syncthreads();

    // ---- out = sigmoid(relu([comp, ss] @ Wc1 + bc1) @ Wc2 + bc2) ----
    {
        int r = tid >> 3;       // 0..31
        int u16 = tid & 7;      // 8 threads × 16 units = 128
        float as[9];
        #pragma unroll
        for (int a = 0; a < 8; ++a) as[a] = compS[r][a];
        as[8] = ssS[r];
        float part = 0.0f;
        #pragma unroll
        for (int i = 0; i < 16; ++i) {
            int u = u16 * 16 + i;
            float h = bc1[u];
            #pragma unroll
            for (int a = 0; a < 9; ++a) h += as[a] * Wc1[a * 128 + u];
            part += fmaxf(h, 0.0f) * Wc2[u];
        }
        part += __shfl_xor(part, 1);
        part += __shfl_xor(part, 2);
        part += __shfl_xor(part, 4);
        if (u16 == 0) {
            float z = part + bc2[0];
            out[gbase + r] = 1.0f / (1.0f + expf(-z));
        }
    }
}

extern "C" void kernel_launch(void* const* d_in, const int* in_sizes, int n_in,
                              void* d_out, int out_size, void* d_ws, size_t ws_size,
                              hipStream_t stream) {
    const float* emb = (const float*)d_in[0];
    const int*   eg  = (const int*)d_in[1];
    const int*   ei  = (const int*)d_in[2];
    const float* W1  = (const float*)d_in[3];
    const float* b1  = (const float*)d_in[4];
    const float* W2  = (const float*)d_in[5];
    const float* b2  = (const float*)d_in[6];
    const float* Ws1 = (const float*)d_in[7];
    const float* bs1 = (const float*)d_in[8];
    const float* Ws2 = (const float*)d_in[9];
    const float* bs2 = (const float*)d_in[10];
    const float* Wc1 = (const float*)d_in[11];
    const float* bc1 = (const float*)d_in[12];
    const float* Wc2 = (const float*)d_in[13];
    const float* bc2 = (const float*)d_in[14];
    float* out = (float*)d_out;
    float* deg = (float*)d_ws;    // NUM_NODES floats of scratch

    zero_deg_kernel<<<(NUM_NODES + 255) / 256, 256, 0, stream>>>(deg);
    degree_kernel<<<(E_CNT + 255) / 256, 256, 0, stream>>>(ei, deg);
    egis_main_kernel<<<G_CNT / ROWS, TPB, 0, stream>>>(
        emb, eg, ei, W1, b1, W2, b2, Ws1, bs1, Ws2, bs2, Wc1, bc1, Wc2, bc2,
        deg, out);
}

// Round 2
// 1886.857 us; speedup vs baseline: 1.2493x; 1.2493x over previous
//
#include <hip/hip_runtime.h>
#include <math.h>

#define E_CNT 800000
#define G_CNT 1000000
#define HIDDEN 256
#define NUM_NODES 100000

#define ROWS 64      // groups per block
#define TPB 256      // 4 waves

typedef __attribute__((ext_vector_type(8))) short bf16x8;   // 8 bf16 = 4 VGPRs
typedef __attribute__((ext_vector_type(4))) float f32x4;

__device__ __forceinline__ short f2bf(float f) {
    union { float f; unsigned u; } v; v.f = f;
    unsigned r = v.u + 0x7fffu + ((v.u >> 16) & 1u);   // RNE
    return (short)(r >> 16);
}

__global__ void zero_deg_kernel(float* __restrict__ deg) {
    int i = blockIdx.x * blockDim.x + threadIdx.x;
    if (i < NUM_NODES) deg[i] = 0.0f;
}

__global__ void degree_kernel(const int* __restrict__ ei, float* __restrict__ deg) {
    int e = blockIdx.x * blockDim.x + threadIdx.x;
    if (e < E_CNT) {
        atomicAdd(&deg[ei[e]], 1.0f);
        atomicAdd(&deg[ei[E_CNT + e]], 1.0f);
    }
}

// W1T[n][k] = bf16(W1[k][n]); contiguous writes, scattered (L2-hot) reads.
__global__ void prep_w1t_kernel(const float* __restrict__ W1, short* __restrict__ w1t) {
    int t = blockIdx.x * blockDim.x + threadIdx.x;   // 65536
    int n = t >> 8, k = t & 255;
    w1t[t] = f2bf(W1[k * 256 + n]);
}

// WS: true -> B-frags from pre-transposed bf16 W1T in workspace (fast path)
//     false -> B-frags gathered from fp32 W1 directly (fallback if ws too small)
template <bool WS>
__launch_bounds__(TPB, 3)
__global__ void egis_main_kernel(
    const float* __restrict__ emb,   // (E, 128)
    const int*   __restrict__ eg,    // (G, 2)
    const int*   __restrict__ ei,    // (2, E)
    const float* __restrict__ W1, const float* __restrict__ b1,
    const float* __restrict__ W2, const float* __restrict__ b2,
    const float* __restrict__ Ws1, const float* __restrict__ bs1,
    const float* __restrict__ Ws2, const float* __restrict__ bs2,
    const float* __restrict__ Wc1, const float* __restrict__ bc1,
    const float* __restrict__ Wc2, const float* __restrict__ bc2,
    const float* __restrict__ deg,
    const short* __restrict__ w1t,   // (256,256) bf16, [n][k]
    float* __restrict__ out)
{
    // pair tile in bf16; row stride 264 (=33*8) breaks power-of-2 bank aliasing
    // and keeps 16B alignment for bf16x8 fragment reads. Reused later for relu(h).
    __shared__ short pairS[ROWS][264];     // 33 KB
    __shared__ short w2tS[16][264];        // W2^T bf16, rows 8..15 zero-padded
    __shared__ float compS[ROWS][8];
    __shared__ float ssS[ROWS];
    __shared__ int g0S[ROWS], g1S[ROWS];

    const int tid = threadIdx.x;
    const int gbase = blockIdx.x * ROWS;

    if (tid < ROWS) {
        g0S[tid] = eg[(gbase + tid) * 2 + 0];
        g1S[tid] = eg[(gbase + tid) * 2 + 1];
    }
    {   // zero w2tS (rows >=8 must be 0 for the padded 16-col MFMA)
        int* w2i = (int*)&w2tS[0][0];
        for (int i = tid; i < (16 * 264) / 2; i += TPB) w2i[i] = 0;
    }
    __syncthreads();

    // ---- gather pair rows -> bf16 LDS; fill W2^T bf16 ----
    {
        const float4* emb4 = (const float4*)emb;
        #pragma unroll
        for (int it = 0; it < (ROWS * 32) / TPB; ++it) {   // 8 iters
            int c = it * TPB + tid;
            int r = c >> 5, c8 = c & 31;                   // 8-float chunk in row
            long src = (c8 < 16) ? ((long)g0S[r] * 32 + c8 * 2)
                                 : ((long)g1S[r] * 32 + (c8 - 16) * 2);
            float4 v0 = emb4[src], v1 = emb4[src + 1];
            bf16x8 h;
            h[0] = f2bf(v0.x); h[1] = f2bf(v0.y); h[2] = f2bf(v0.z); h[3] = f2bf(v0.w);
            h[4] = f2bf(v1.x); h[5] = f2bf(v1.y); h[6] = f2bf(v1.z); h[7] = f2bf(v1.w);
            *(bf16x8*)&pairS[r][c8 * 8] = h;
        }
        #pragma unroll
        for (int it = 0; it < 2048 / TPB; ++it) {          // W2 (256x8)
            int idx = it * TPB + tid;
            int k = idx >> 3, n = idx & 7;
            w2tS[n][k] = f2bf(W2[idx]);
        }
    }
    __syncthreads();

    // ---- hidden = relu(pair @ W1 + b1) via MFMA 16x16x32 bf16 ----
    // wave w: col-half ch=w&1 (128 cols), row-tiles rtA=w>>1, rtB=rtA+2.
    // A-frag: row=lane&15, k=8*(lane>>4)+v (contiguous) ; D: row=(lane>>4)*4+i, col=lane&15.
    const int wv = tid >> 6, lane = tid & 63;
    const int ch = wv & 1, n0 = ch * 128;
    const int rtA = wv >> 1, rtB = rtA + 2;
    const int l16 = lane & 15, lh = lane >> 4;

    f32x4 accA[8], accB[8];
    #pragma unroll
    for (int f = 0; f < 8; ++f) {
        float bv = b1[n0 + f * 16 + l16];
        accA[f] = (f32x4){bv, bv, bv, bv};
        accB[f] = accA[f];
    }

    const bf16x8* pS8 = (const bf16x8*)&pairS[0][0];   // row stride 33 chunks
    const int aBaseA = (rtA * 16 + l16) * 33 + lh;
    const int aBaseB = (rtB * 16 + l16) * 33 + lh;

    if constexpr (WS) {
        const bf16x8* B8 = (const bf16x8*)w1t;          // [n][k], stride 32 chunks
        const int bBase = (n0 + l16) * 32 + lh;
        #pragma unroll 2
        for (int ks = 0; ks < 8; ++ks) {
            bf16x8 aA = pS8[aBaseA + ks * 4];
            bf16x8 aB = pS8[aBaseB + ks * 4];
            #pragma unroll
            for (int f = 0; f < 8; ++f) {
                bf16x8 b = B8[bBase + f * 512 + ks * 4];
                accA[f] = __builtin_amdgcn_mfma_f32_16x16x32_bf16(aA, b, accA[f], 0, 0, 0);
                accB[f] = __builtin_amdgcn_mfma_f32_16x16x32_bf16(aB, b, accB[f], 0, 0, 0);
            }
        }
    } else {
        #pragma unroll 1
        for (int ks = 0; ks < 8; ++ks) {
            bf16x8 aA = pS8[aBaseA + ks * 4];
            bf16x8 aB = pS8[aBaseB + ks * 4];
            for (int f = 0; f < 8; ++f) {
                int n = n0 + f * 16 + l16;
                bf16x8 b;
                #pragma unroll
                for (int v = 0; v < 8; ++v)
                    b[v] = f2bf(W1[(ks * 32 + lh * 8 + v) * 256 + n]);
                accA[f] = __builtin_amdgcn_mfma_f32_16x16x32_bf16(aA, b, accA[f], 0, 0, 0);
                accB[f] = __builtin_amdgcn_mfma_f32_16x16x32_bf16(aB, b, accB[f], 0, 0, 0);
            }
        }
    }

    __syncthreads();   // all waves done reading pair tile

    // ---- store relu(h) bf16 back into pairS (now the h tile) ----
    #pragma unroll
    for (int f = 0; f < 8; ++f) {
        #pragma unroll
        for (int i = 0; i < 4; ++i) {
            pairS[rtA * 16 + lh * 4 + i][n0 + f * 16 + l16] = f2bf(fmaxf(accA[f][i], 0.f));
            pairS[rtB * 16 + lh * 4 + i][n0 + f * 16 + l16] = f2bf(fmaxf(accB[f][i], 0.f));
        }
    }
    __syncthreads();

    // ---- comp = relu(h @ W2 + b2): one 16-row tile per wave, N padded to 16 ----
    {
        float c0 = (l16 < 8) ? b2[l16] : 0.f;
        f32x4 acc2 = (f32x4){c0, c0, c0, c0};
        const int aBase = (wv * 16 + l16) * 33 + lh;
        const bf16x8* w2S8 = (const bf16x8*)&w2tS[0][0];
        const int bBase = l16 * 33 + lh;
        #pragma unroll
        for (int ks = 0; ks < 8; ++ks) {
            bf16x8 a = pS8[aBase + ks * 4];
            bf16x8 b = w2S8[bBase + ks * 4];
            acc2 = __builtin_amdgcn_mfma_f32_16x16x32_bf16(a, b, acc2, 0, 0, 0);
        }
        if (l16 < 8) {
            #pragma unroll
            for (int i = 0; i < 4; ++i)
                compS[wv * 16 + lh * 4 + i][l16] = fmaxf(acc2[i], 0.f);
        }
    }

    // ---- structural score (4 threads per row) ----
    {
        int r = tid >> 2, q = tid & 3;
        int g0 = g0S[r], g1 = g1S[r];
        float s0 = deg[ei[g0]];
        float s1 = deg[ei[E_CNT + g0]];
        float s2 = deg[ei[g1]];
        float s3 = deg[ei[E_CNT + g1]];
        float part = 0.f;
        #pragma unroll
        for (int i = 0; i < 16; ++i) {
            int u = q * 16 + i;
            float h = bs1[u] + s0 * Ws1[u] + s1 * Ws1[64 + u]
                             + s2 * Ws1[128 + u] + s3 * Ws1[192 + u];
            part += fmaxf(h, 0.f) * Ws2[u];
        }
        part += __shfl_xor(part, 1);
        part += __shfl_xor(part, 2);
        if (q == 0) ssS[r] = part + bs2[0];
    }
    __syncthreads();

    // ---- out = sigmoid(relu([comp,ss] @ Wc1 + bc1) @ Wc2 + bc2) ----
    {
        int r = tid >> 2, q = tid & 3;
        float as[9];
        #pragma unroll
        for (int a = 0; a < 8; ++a) as[a] = compS[r][a];
        as[8] = ssS[r];
        float part = 0.f;
        for (int i = 0; i < 32; ++i) {
            int u = q * 32 + i;
            float h = bc1[u];
            #pragma unroll
            for (int a = 0; a < 9; ++a) h += as[a] * Wc1[a * 128 + u];
            part += fmaxf(h, 0.f) * Wc2[u];
        }
        part += __shfl_xor(part, 1);
        part += __shfl_xor(part, 2);
        if (q == 0) out[gbase + r] = 1.f / (1.f + expf(-(part + bc2[0])));
    }
}

extern "C" void kernel_launch(void* const* d_in, const int* in_sizes, int n_in,
                              void* d_out, int out_size, void* d_ws, size_t ws_size,
                              hipStream_t stream) {
    const float* emb = (const float*)d_in[0];
    const int*   eg  = (const int*)d_in[1];
    const int*   ei  = (const int*)d_in[2];
    const float* W1  = (const float*)d_in[3];
    const float* b1  = (const float*)d_in[4];
    const float* W2  = (const float*)d_in[5];
    const float* b2  = (const float*)d_in[6];
    const float* Ws1 = (const float*)d_in[7];
    const float* bs1 = (const float*)d_in[8];
    const float* Ws2 = (const float*)d_in[9];
    const float* bs2 = (const float*)d_in[10];
    const float* Wc1 = (const float*)d_in[11];
    const float* bc1 = (const float*)d_in[12];
    const float* Wc2 = (const float*)d_in[13];
    const float* bc2 = (const float*)d_in[14];
    float* out = (float*)d_out;

    // ws layout: deg (400000 B) | align 256 | W1T bf16 (131072 B)
    float* deg = (float*)d_ws;
    size_t w1tOff = ((size_t)NUM_NODES * 4 + 255) & ~(size_t)255;
    short* w1t = (short*)((char*)d_ws + w1tOff);
    bool haveWs = ws_size >= w1tOff + 256 * 256 * sizeof(short);

    zero_deg_kernel<<<(NUM_NODES + 255) / 256, 256, 0, stream>>>(deg);
    degree_kernel<<<(E_CNT + 255) / 256, 256, 0, stream>>>(ei, deg);
    if (haveWs) {
        prep_w1t_kernel<<<65536 / 256, 256, 0, stream>>>(W1, w1t);
        egis_main_kernel<true><<<G_CNT / ROWS, TPB, 0, stream>>>(
            emb, eg, ei, W1, b1, W2, b2, Ws1, bs1, Ws2, bs2, Wc1, bc1, Wc2, bc2,
            deg, w1t, out);
    } else {
        egis_main_kernel<false><<<G_CNT / ROWS, TPB, 0, stream>>>(
            emb, eg, ei, W1, b1, W2, b2, Ws1, bs1, Ws2, bs2, Wc1, bc1, Wc2, bc2,
            deg, (const short*)nullptr, out);
    }
}

// Round 3
// 1517.306 us; speedup vs baseline: 1.5536x; 1.2436x over previous
//
#include <hip/hip_runtime.h>
#include <math.h>

#define E_CNT 800000
#define G_CNT 1000000
#define NUM_NODES 100000

#define ROWS 32      // groups per block
#define TPB 256      // 4 waves

typedef __attribute__((ext_vector_type(8))) short bf16x8;   // 8 bf16 = 4 VGPRs
typedef __attribute__((ext_vector_type(4))) float f32x4;

__device__ __forceinline__ short f2bf(float f) {
    union { float f; unsigned u; } v; v.f = f;
    unsigned r = v.u + 0x7fffu + ((v.u >> 16) & 1u);   // RNE
    return (short)(r >> 16);
}

__global__ void zero_deg_kernel(float* __restrict__ deg) {
    int i = blockIdx.x * blockDim.x + threadIdx.x;
    if (i < NUM_NODES) deg[i] = 0.0f;
}

__global__ void degree_kernel(const int* __restrict__ ei, float* __restrict__ deg) {
    int e = blockIdx.x * blockDim.x + threadIdx.x;
    if (e < E_CNT) {
        atomicAdd(&deg[ei[e]], 1.0f);
        atomicAdd(&deg[ei[E_CNT + e]], 1.0f);
    }
}

// W1T[n][k] = bf16(W1[k][n])
__global__ void prep_w1t_kernel(const float* __restrict__ W1, short* __restrict__ w1t) {
    int t = blockIdx.x * blockDim.x + threadIdx.x;   // 65536
    int n = t >> 8, k = t & 255;
    w1t[t] = f2bf(W1[k * 256 + n]);
}

// emb fp32 (800000x128, 410 MB) -> bf16 (205 MB, fits L3)
__global__ void prep_emb_kernel(const float* __restrict__ emb, short* __restrict__ ebf) {
    long t = (long)blockIdx.x * blockDim.x + threadIdx.x;   // 12.8M threads, 8 elems each
    const float4* e4 = (const float4*)emb;
    float4 v0 = e4[t * 2], v1 = e4[t * 2 + 1];
    bf16x8 h;
    h[0] = f2bf(v0.x); h[1] = f2bf(v0.y); h[2] = f2bf(v0.z); h[3] = f2bf(v0.w);
    h[4] = f2bf(v1.x); h[5] = f2bf(v1.y); h[6] = f2bf(v1.z); h[7] = f2bf(v1.w);
    *(bf16x8*)&ebf[t * 8] = h;
}

// MODE 2: gather from bf16 emb copy + B from w1t (fast path)
// MODE 1: gather from fp32 emb (inline cvt) + B from w1t
// MODE 0: no workspace tables at all
//
// pairS layout: 32 rows x 256 bf16, linear 512B row stride (no pad).
// Chunk swizzle: LDS chunk c of row r holds LOGICAL chunk (c ^ (r&7))
// (chunks = 16B = 8 bf16). All readers/writers apply the same XOR ->
// conflict-free ds_read_b128 A-fragments despite power-of-2 stride.
template <int MODE>
__launch_bounds__(TPB, 6)
__global__ void egis_main_kernel(
    const float* __restrict__ emb,   // (E, 128)
    const int*   __restrict__ eg,    // (G, 2)
    const int*   __restrict__ ei,    // (2, E)
    const float* __restrict__ W1, const float* __restrict__ b1,
    const float* __restrict__ W2, const float* __restrict__ b2,
    const float* __restrict__ Ws1, const float* __restrict__ bs1,
    const float* __restrict__ Ws2, const float* __restrict__ bs2,
    const float* __restrict__ Wc1, const float* __restrict__ bc1,
    const float* __restrict__ Wc2, const float* __restrict__ bc2,
    const float* __restrict__ deg,
    const short* __restrict__ w1t,   // (256,256) bf16, [n][k]
    const short* __restrict__ ebf,   // (E,128) bf16
    float* __restrict__ out)
{
    __shared__ short pairS[ROWS][256];     // 16 KB, swizzled; later holds relu(h)
    __shared__ short w2tS[16][264];        // W2^T bf16, rows 8..15 zero
    __shared__ float compS[ROWS][8];
    __shared__ float ssS[ROWS];
    __shared__ int g0S[ROWS], g1S[ROWS];

    const int tid = threadIdx.x;
    const int gbase = blockIdx.x * ROWS;
    const int wv = tid >> 6, lane = tid & 63, l16 = lane & 15, lh = lane >> 4;

    if (tid < ROWS) {
        int2 g = ((const int2*)eg)[gbase + tid];
        g0S[tid] = g.x; g1S[tid] = g.y;
    }
    // zero only rows 8..15 of w2tS (rows 0..7 are fully overwritten below)
    for (int i = tid; i < (8 * 264) / 2; i += TPB) ((int*)&w2tS[8][0])[i] = 0;
    __syncthreads();

    // ---- gather pair rows into swizzled bf16 LDS ----
    if constexpr (MODE == 2) {
        #pragma unroll
        for (int it = 0; it < 4; ++it) {
            int idx = it * TPB + tid;          // 0..1023 = row*32 + chunk
            int r = idx >> 5, rc = idx & 31;
            int gi = rc ^ (r & 7);             // logical chunk (bit4 = which half)
            int grow = (gi & 16) ? g1S[r] : g0S[r];
            bf16x8 h = *(const bf16x8*)(ebf + (long)grow * 128 + (gi & 15) * 8);
            *(bf16x8*)&pairS[r][rc * 8] = h;
        }
    } else {
        #pragma unroll
        for (int it = 0; it < 4; ++it) {
            int idx = it * TPB + tid;
            int r = idx >> 5, rc = idx & 31;
            int gi = rc ^ (r & 7);
            int grow = (gi & 16) ? g1S[r] : g0S[r];
            const float4* s4 = (const float4*)(emb + (long)grow * 128 + (gi & 15) * 8);
            float4 v0 = s4[0], v1 = s4[1];
            bf16x8 h;
            h[0] = f2bf(v0.x); h[1] = f2bf(v0.y); h[2] = f2bf(v0.z); h[3] = f2bf(v0.w);
            h[4] = f2bf(v1.x); h[5] = f2bf(v1.y); h[6] = f2bf(v1.z); h[7] = f2bf(v1.w);
            *(bf16x8*)&pairS[r][rc * 8] = h;
        }
    }

    // ---- fill W2^T rows 0..7 ----
    #pragma unroll
    for (int it = 0; it < 2048 / TPB; ++it) {
        int idx = it * TPB + tid;              // k*8 + n
        w2tS[idx & 7][idx >> 3] = f2bf(W2[idx]);
    }

    // ---- structural score EARLY: its 2-deep random loads overlap the gather ----
    {
        int r = tid >> 3, q = tid & 7;
        int g0 = g0S[r], g1 = g1S[r];
        float s0 = deg[ei[g0]];
        float s1 = deg[ei[E_CNT + g0]];
        float s2 = deg[ei[g1]];
        float s3 = deg[ei[E_CNT + g1]];
        float part = 0.f;
        #pragma unroll
        for (int i = 0; i < 8; ++i) {
            int u = q * 8 + i;
            float h = bs1[u] + s0 * Ws1[u] + s1 * Ws1[64 + u]
                             + s2 * Ws1[128 + u] + s3 * Ws1[192 + u];
            part += fmaxf(h, 0.f) * Ws2[u];
        }
        part += __shfl_xor(part, 1);
        part += __shfl_xor(part, 2);
        part += __shfl_xor(part, 4);
        if (q == 0) ssS[r] = part + bs2[0];
    }
    __syncthreads();

    // ---- hidden = relu(pair @ W1 + b1), MFMA 16x16x32 bf16 ----
    // wave wv: col-half ch = wv&1 (128 cols), row-tile rt = wv>>1 (16 rows)
    const int ch = wv & 1, n0 = ch * 128, rt = wv >> 1;

    f32x4 acc[8];
    #pragma unroll
    for (int f = 0; f < 8; ++f) {
        float bv = b1[n0 + f * 16 + l16];
        acc[f] = (f32x4){bv, bv, bv, bv};
    }

    const short* aRow = &pairS[rt * 16 + l16][0];
    const int axr = l16 & 7;   // (row & 7) for A reads

    if constexpr (MODE >= 1) {
        const bf16x8* B8 = (const bf16x8*)w1t;          // [n][k], 32 chunks/row
        const int bBase = (n0 + l16) * 32 + lh;
        #pragma unroll 2
        for (int ks = 0; ks < 8; ++ks) {
            bf16x8 a = *(const bf16x8*)(aRow + ((ks * 4 + lh) ^ axr) * 8);
            #pragma unroll
            for (int f = 0; f < 8; ++f) {
                bf16x8 b = B8[bBase + f * 512 + ks * 4];
                acc[f] = __builtin_amdgcn_mfma_f32_16x16x32_bf16(a, b, acc[f], 0, 0, 0);
            }
        }
    } else {
        #pragma unroll 1
        for (int ks = 0; ks < 8; ++ks) {
            bf16x8 a = *(const bf16x8*)(aRow + ((ks * 4 + lh) ^ axr) * 8);
            for (int f = 0; f < 8; ++f) {
                int n = n0 + f * 16 + l16;
                bf16x8 b;
                #pragma unroll
                for (int v = 0; v < 8; ++v)
                    b[v] = f2bf(W1[(ks * 32 + lh * 8 + v) * 256 + n]);
                acc[f] = __builtin_amdgcn_mfma_f32_16x16x32_bf16(a, b, acc[f], 0, 0, 0);
            }
        }
    }
    __syncthreads();   // all waves done reading pair tile

    // ---- store relu(h) bf16 back into pairS (same XOR convention) ----
    #pragma unroll
    for (int f = 0; f < 8; ++f) {
        #pragma unroll
        for (int i = 0; i < 4; ++i) {
            int row = rt * 16 + lh * 4 + i;    // D layout: row = (lane>>4)*4+i
            int col = n0 + f * 16 + l16;       //           col = lane&15
            pairS[row][col ^ ((row & 7) << 3)] = f2bf(fmaxf(acc[f][i], 0.f));
        }
    }
    __syncthreads();

    // ---- comp = relu(h @ W2 + b2): row-tile wv (waves 0-1 only) ----
    if (wv < 2) {
        float c0 = (l16 < 8) ? b2[l16] : 0.f;
        f32x4 a2 = (f32x4){c0, c0, c0, c0};
        const short* hRow = &pairS[wv * 16 + l16][0];   // (row&7) == l16&7 == axr
        const short* w2p = &w2tS[l16][0];
        #pragma unroll
        for (int ks = 0; ks < 8; ++ks) {
            bf16x8 a = *(const bf16x8*)(hRow + ((ks * 4 + lh) ^ axr) * 8);
            bf16x8 b = *(const bf16x8*)(w2p + (ks * 4 + lh) * 8);
            a2 = __builtin_amdgcn_mfma_f32_16x16x32_bf16(a, b, a2, 0, 0, 0);
        }
        if (l16 < 8) {
            #pragma unroll
            for (int i = 0; i < 4; ++i)
                compS[wv * 16 + lh * 4 + i][l16] = fmaxf(a2[i], 0.f);
        }
    }
    __syncthreads();

    // ---- out = sigmoid(relu([comp, ss] @ Wc1 + bc1) @ Wc2 + bc2) ----
    {
        int r = tid >> 3, q = tid & 7;
        float as[9];
        #pragma unroll
        for (int a = 0; a < 8; ++a) as[a] = compS[r][a];
        as[8] = ssS[r];
        float part = 0.f;
        #pragma unroll
        for (int i = 0; i < 16; ++i) {
            int u = q * 16 + i;
            float h = bc1[u];
            #pragma unroll
            for (int a = 0; a < 9; ++a) h += as[a] * Wc1[a * 128 + u];
            part += fmaxf(h, 0.f) * Wc2[u];
        }
        part += __shfl_xor(part, 1);
        part += __shfl_xor(part, 2);
        part += __shfl_xor(part, 4);
        if (q == 0) out[gbase + r] = 1.f / (1.f + expf(-(part + bc2[0])));
    }
}

extern "C" void kernel_launch(void* const* d_in, const int* in_sizes, int n_in,
                              void* d_out, int out_size, void* d_ws, size_t ws_size,
                              hipStream_t stream) {
    const float* emb = (const float*)d_in[0];
    const int*   eg  = (const int*)d_in[1];
    const int*   ei  = (const int*)d_in[2];
    const float* W1  = (const float*)d_in[3];
    const float* b1  = (const float*)d_in[4];
    const float* W2  = (const float*)d_in[5];
    const float* b2  = (const float*)d_in[6];
    const float* Ws1 = (const float*)d_in[7];
    const float* bs1 = (const float*)d_in[8];
    const float* Ws2 = (const float*)d_in[9];
    const float* bs2 = (const float*)d_in[10];
    const float* Wc1 = (const float*)d_in[11];
    const float* bc1 = (const float*)d_in[12];
    const float* Wc2 = (const float*)d_in[13];
    const float* bc2 = (const float*)d_in[14];
    float* out = (float*)d_out;

    // ws: deg (400128 B) | w1t bf16 (131072 B) | ebf bf16 (204800000 B)
    float* deg = (float*)d_ws;
    size_t degB = ((size_t)NUM_NODES * 4 + 255) & ~(size_t)255;
    short* w1t = (short*)((char*)d_ws + degB);
    size_t w1tB = 256 * 256 * sizeof(short);
    short* ebf = (short*)((char*)d_ws + degB + w1tB);
    size_t embB = (size_t)E_CNT * 128 * sizeof(short);

    int mode = (ws_size >= degB + w1tB + embB) ? 2
             : (ws_size >= degB + w1tB) ? 1 : 0;

    zero_deg_kernel<<<(NUM_NODES + 255) / 256, 256, 0, stream>>>(deg);
    degree_kernel<<<(E_CNT + 255) / 256, 256, 0, stream>>>(ei, deg);
    if (mode >= 1) prep_w1t_kernel<<<65536 / 256, 256, 0, stream>>>(W1, w1t);
    if (mode == 2) prep_emb_kernel<<<50000, 256, 0, stream>>>(emb, ebf);

    switch (mode) {
    case 2:
        egis_main_kernel<2><<<G_CNT / ROWS, TPB, 0, stream>>>(
            emb, eg, ei, W1, b1, W2, b2, Ws1, bs1, Ws2, bs2, Wc1, bc1, Wc2, bc2,
            deg, w1t, ebf, out);
        break;
    case 1:
        egis_main_kernel<1><<<G_CNT / ROWS, TPB, 0, stream>>>(
            emb, eg, ei, W1, b1, W2, b2, Ws1, bs1, Ws2, bs2, Wc1, bc1, Wc2, bc2,
            deg, w1t, (const short*)nullptr, out);
        break;
    default:
        egis_main_kernel<0><<<G_CNT / ROWS, TPB, 0, stream>>>(
            emb, eg, ei, W1, b1, W2, b2, Ws1, bs1, Ws2, bs2, Wc1, bc1, Wc2, bc2,
            deg, (const short*)nullptr, (const short*)nullptr, out);
        break;
    }
}